// Round 1
// baseline (105.172 us; speedup 1.0000x reference)
//
#include <hip/hip_runtime.h>

// Chamfer reconstruction loss, B=16, P=Q=4096, 3-D points.
// loss = sum_b [ mean_i min_j d(x_i,y_j) + mean_j min_i d ] / B
//      = (sum of all 131072 per-point nearest-sq-dists) / 65536   (since P==Q, equal segments)

#define NB 16
#define NP 4096
#define NPTS 65536          // NB*NP (== NB*NQ)
#define JTILE 1024          // target points staged in LDS per block
#define INV128 0.0078125f   // 1/128 : gt normalize (c-128)/128 = c/128 - 1

__global__ __launch_bounds__(256) void init_kernel(unsigned int* __restrict__ mins,
                                                   float* __restrict__ out) {
    int i = blockIdx.x * 1024 + threadIdx.x * 4;   // 128 blocks cover 131072
    uint4* p = (uint4*)(mins + i);
    *p = make_uint4(0x7F800000u, 0x7F800000u, 0x7F800000u, 0x7F800000u); // +inf
    if (blockIdx.x == 0 && threadIdx.x == 0) out[0] = 0.0f;
}

// grid = 512 blocks: [0,256) dir0 (queries=gen, targets=gt), [256,512) dir1 (swapped).
// block decode: b = bid>>4 (batch), qtile = (bid>>2)&3, ttile = bid&3.
// Each thread owns 4 query rows (strided by 256); min over the block's 1024-target
// LDS chunk; cross-chunk combine via atomicMin on uint float-bits (d clamped >= 0).
__global__ __launch_bounds__(256) void chamfer_kernel(const float* __restrict__ gen,
                                                      const float* __restrict__ label,
                                                      unsigned int* __restrict__ mins) {
    __shared__ float4 sy[JTILE];   // (-2x, -2y, -2z, x^2+y^2+z^2)

    int bid = blockIdx.x;
    const int dir = bid >> 8;
    bid &= 255;
    const int b     = bid >> 4;
    const int qtile = (bid >> 2) & 3;
    const int ttile = bid & 3;
    const int t     = threadIdx.x;
    const int base  = b * NP;
    const int tbase = base + ttile * JTILE;

    // --- stage target chunk into LDS (normalize gt on the fly for dir0) ---
    #pragma unroll
    for (int k = 0; k < 4; ++k) {
        int idx = t + k * 256;
        float x, y, z;
        if (dir == 0) {
            const float* row = label + (size_t)(tbase + idx) * 5;
            x = fmaf(row[1], INV128, -1.0f);
            y = fmaf(row[2], INV128, -1.0f);
            z = fmaf(row[3], INV128, -1.0f);
        } else {
            const float* row = gen + (size_t)(tbase + idx) * 3;
            x = row[0]; y = row[1]; z = row[2];
        }
        float n2 = fmaf(x, x, fmaf(y, y, z * z));
        sy[idx] = make_float4(-2.0f * x, -2.0f * y, -2.0f * z, n2);
    }
    __syncthreads();

    // --- load 4 query rows into registers ---
    float qx[4], qy[4], qz[4], q2[4], mn[4];
    const int q0 = base + qtile * JTILE + t;
    #pragma unroll
    for (int r = 0; r < 4; ++r) {
        int qi = q0 + r * 256;
        float x, y, z;
        if (dir == 0) {
            const float* row = gen + (size_t)qi * 3;
            x = row[0]; y = row[1]; z = row[2];
        } else {
            const float* row = label + (size_t)qi * 5;
            x = fmaf(row[1], INV128, -1.0f);
            y = fmaf(row[2], INV128, -1.0f);
            z = fmaf(row[3], INV128, -1.0f);
        }
        qx[r] = x; qy[r] = y; qz[r] = z;
        q2[r] = fmaf(x, x, fmaf(y, y, z * z));
        mn[r] = __int_as_float(0x7F800000);  // +inf
    }

    // --- inner loop: 4 VALU per pair (3 fma + 1 min); LDS broadcast reads ---
    for (int j = 0; j < JTILE; j += 4) {
        #pragma unroll
        for (int u = 0; u < 4; ++u) {
            float4 yv = sy[j + u];
            #pragma unroll
            for (int r = 0; r < 4; ++r) {
                // t^2 - 2 q.t  (q^2 added after the min — it's row-constant)
                float v = fmaf(qz[r], yv.z, fmaf(qy[r], yv.y, fmaf(qx[r], yv.x, yv.w)));
                mn[r] = fminf(mn[r], v);
            }
        }
    }

    unsigned int* om = mins + dir * NPTS;
    #pragma unroll
    for (int r = 0; r < 4; ++r) {
        float d = fmaxf(mn[r] + q2[r], 0.0f);  // clamp: keep uint order == float order
        atomicMin(&om[q0 + r * 256], __float_as_uint(d));
    }
}

__global__ __launch_bounds__(256) void reduce_kernel(const unsigned int* __restrict__ mins,
                                                     float* __restrict__ out) {
    int i = blockIdx.x * 1024 + threadIdx.x * 4;   // 128 blocks cover 131072
    const float4 v = *(const float4*)((const float*)mins + i);
    float s = (v.x + v.y) + (v.z + v.w);
    #pragma unroll
    for (int off = 32; off > 0; off >>= 1) s += __shfl_down(s, off);
    __shared__ float wsum[4];
    int w = threadIdx.x >> 6;
    if ((threadIdx.x & 63) == 0) wsum[w] = s;
    __syncthreads();
    if (threadIdx.x == 0) {
        atomicAdd(out, (wsum[0] + wsum[1] + wsum[2] + wsum[3]) * (1.0f / 65536.0f));
    }
}

extern "C" void kernel_launch(void* const* d_in, const int* in_sizes, int n_in,
                              void* d_out, int out_size, void* d_ws, size_t ws_size,
                              hipStream_t stream) {
    const float* gen   = (const float*)d_in[0];   // [B*P, 3] fp32
    // d_in[1] = batch_gen (int32) — unused: segments are contiguous equal-size
    const float* label = (const float*)d_in[2];   // [B*Q, 5] fp32
    unsigned int* mins = (unsigned int*)d_ws;     // 131072 uints = 512 KB
    float* out = (float*)d_out;

    init_kernel<<<128, 256, 0, stream>>>(mins, out);
    chamfer_kernel<<<512, 256, 0, stream>>>(gen, label, mins);
    reduce_kernel<<<128, 256, 0, stream>>>(mins, out);
}

// Round 2
// 104.740 us; speedup vs baseline: 1.0041x; 1.0041x over previous
//
#include <hip/hip_runtime.h>

// Chamfer reconstruction loss, B=16, P=Q=4096, 3-D points.
// loss = (sum of all 131072 per-point nearest-sq-dists) / 65536   (P==Q, equal segments)
//
// chamfer_kernel: packed-fp32 (v_pk_fma_f32) inner loop, 2 instr/pair:
//   per 2 targets x 2-row pair: 6 pk_fma + 2 v_min3  (covers 4 pair-ops).
// 16 query rows/thread (8 f2 pairs) amortize the broadcast LDS reads;
// explicit 2-target register double-buffer hides ds_read latency.

#define NB 16
#define NP 4096
#define NPTS 65536          // NB*NP per direction
#define THREADS 256
#define ROWS 16             // query rows per thread
#define PAIRS 8             // ROWS/2 packed f2 pairs
#define JT 256              // targets staged in LDS per block
#define TTILES 16           // NP/JT
#define INV128 0.0078125f   // gt normalize: c/128 - 1

typedef __attribute__((ext_vector_type(2))) float f2;

__device__ __forceinline__ f2 splat2(float v) { f2 r; r.x = v; r.y = v; return r; }

__global__ __launch_bounds__(256) void init_kernel(unsigned int* __restrict__ mins,
                                                   float* __restrict__ out) {
    int i = blockIdx.x * 1024 + threadIdx.x * 4;   // 128 blocks cover 131072
    uint4* p = (uint4*)(mins + i);
    *p = make_uint4(0x7F800000u, 0x7F800000u, 0x7F800000u, 0x7F800000u); // +inf
    if (blockIdx.x == 0 && threadIdx.x == 0) out[0] = 0.0f;
}

// grid = 512 blocks: [0,256) dir0 (queries=gen, targets=gt), [256,512) dir1 (swapped).
// decode: b = bid>>4 (batch), tt = bid&15 (target tile). qtiles=1: each block's
// 256 threads x 16 rows cover the full 4096 queries of the batch.
__global__ __launch_bounds__(THREADS) void chamfer_kernel(const float* __restrict__ gen,
                                                          const float* __restrict__ label,
                                                          unsigned int* __restrict__ mins) {
    __shared__ float4 sy[JT];   // (-2x, -2y, -2z, |t|^2)

    int bid = blockIdx.x;
    const int dir = bid >> 8;
    bid &= 255;
    const int b  = bid >> 4;
    const int tt = bid & 15;
    const int t  = threadIdx.x;
    const int base = b * NP;

    // --- stage JT=256 targets (one per thread) ---
    {
        int tg = base + tt * JT + t;
        float x, y, z;
        if (dir == 0) {
            const float* row = label + (size_t)tg * 5;
            x = fmaf(row[1], INV128, -1.0f);
            y = fmaf(row[2], INV128, -1.0f);
            z = fmaf(row[3], INV128, -1.0f);
        } else {
            const float* row = gen + (size_t)tg * 3;
            x = row[0]; y = row[1]; z = row[2];
        }
        sy[t] = make_float4(-2.0f * x, -2.0f * y, -2.0f * z,
                            fmaf(x, x, fmaf(y, y, z * z)));
    }

    // --- load 16 query rows as 8 packed f2 pairs ---
    f2 qx[PAIRS], qy[PAIRS], qz[PAIRS], q2[PAIRS], mn[PAIRS];
    #pragma unroll
    for (int p = 0; p < PAIRS; ++p) {
        #pragma unroll
        for (int h = 0; h < 2; ++h) {
            int qi = base + t + (2 * p + h) * 256;
            float x, y, z;
            if (dir == 0) {
                const float* row = gen + (size_t)qi * 3;
                x = row[0]; y = row[1]; z = row[2];
            } else {
                const float* row = label + (size_t)qi * 5;
                x = fmaf(row[1], INV128, -1.0f);
                y = fmaf(row[2], INV128, -1.0f);
                z = fmaf(row[3], INV128, -1.0f);
            }
            float n2 = fmaf(x, x, fmaf(y, y, z * z));
            if (h == 0) { qx[p].x = x; qy[p].x = y; qz[p].x = z; q2[p].x = n2; }
            else        { qx[p].y = x; qy[p].y = y; qz[p].y = z; q2[p].y = n2; }
        }
        mn[p] = splat2(__int_as_float(0x7F800000));  // +inf
    }
    __syncthreads();

    // --- inner loop: 2 targets/iter, register double-buffered LDS broadcast ---
    float4 c0 = sy[0], c1 = sy[1];
    #pragma unroll 2
    for (int j = 0; j < JT; j += 2) {
        int jn = (j + 2) & (JT - 1);        // wrap: last prefetch unused
        float4 n0 = sy[jn], n1 = sy[jn + 1];

        f2 x0 = splat2(c0.x), y0 = splat2(c0.y), z0 = splat2(c0.z), w0 = splat2(c0.w);
        f2 x1 = splat2(c1.x), y1 = splat2(c1.y), z1 = splat2(c1.z), w1 = splat2(c1.w);

        #pragma unroll
        for (int p = 0; p < PAIRS; ++p) {
            // d = |t|^2 - 2 q.t  (q^2 added after the min — row-constant)
            f2 a = __builtin_elementwise_fma(qx[p], x0, w0);
            a = __builtin_elementwise_fma(qy[p], y0, a);
            a = __builtin_elementwise_fma(qz[p], z0, a);
            f2 bv = __builtin_elementwise_fma(qx[p], x1, w1);
            bv = __builtin_elementwise_fma(qy[p], y1, bv);
            bv = __builtin_elementwise_fma(qz[p], z1, bv);
            // fminf(fminf(a,b),mn) per lane -> v_min3_f32
            mn[p] = __builtin_elementwise_min(__builtin_elementwise_min(a, bv), mn[p]);
        }
        c0 = n0; c1 = n1;
    }

    // --- epilogue: add q^2, clamp >=0 (uint order == float order), atomicMin ---
    unsigned int* om = mins + dir * NPTS;
    #pragma unroll
    for (int p = 0; p < PAIRS; ++p) {
        f2 d = mn[p] + q2[p];
        float d0 = fmaxf(d.x, 0.0f);
        float d1 = fmaxf(d.y, 0.0f);
        atomicMin(&om[base + t + (2 * p) * 256], __float_as_uint(d0));
        atomicMin(&om[base + t + (2 * p + 1) * 256], __float_as_uint(d1));
    }
}

__global__ __launch_bounds__(256) void reduce_kernel(const unsigned int* __restrict__ mins,
                                                     float* __restrict__ out) {
    int i = blockIdx.x * 1024 + threadIdx.x * 4;   // 128 blocks cover 131072
    const float4 v = *(const float4*)((const float*)mins + i);
    float s = (v.x + v.y) + (v.z + v.w);
    #pragma unroll
    for (int off = 32; off > 0; off >>= 1) s += __shfl_down(s, off);
    __shared__ float wsum[4];
    int w = threadIdx.x >> 6;
    if ((threadIdx.x & 63) == 0) wsum[w] = s;
    __syncthreads();
    if (threadIdx.x == 0) {
        atomicAdd(out, (wsum[0] + wsum[1] + wsum[2] + wsum[3]) * (1.0f / 65536.0f));
    }
}

extern "C" void kernel_launch(void* const* d_in, const int* in_sizes, int n_in,
                              void* d_out, int out_size, void* d_ws, size_t ws_size,
                              hipStream_t stream) {
    const float* gen   = (const float*)d_in[0];   // [B*P, 3] fp32
    // d_in[1] = batch_gen (int32) — unused: segments are contiguous equal-size
    const float* label = (const float*)d_in[2];   // [B*Q, 5] fp32
    unsigned int* mins = (unsigned int*)d_ws;     // 131072 uints = 512 KB
    float* out = (float*)d_out;

    init_kernel<<<128, 256, 0, stream>>>(mins, out);
    chamfer_kernel<<<512, THREADS, 0, stream>>>(gen, label, mins);
    reduce_kernel<<<128, 256, 0, stream>>>(mins, out);
}

// Round 3
// 104.573 us; speedup vs baseline: 1.0057x; 1.0016x over previous
//
#include <hip/hip_runtime.h>

// Chamfer reconstruction loss, B=16, P=Q=4096, 3-D points.
// loss = (sum of all 131072 per-point nearest-sq-dists) / 65536   (P==Q, equal segments)
//
// Inner loop is forced v_pk_fma_f32 (VOP3P) via inline asm:
//   queries packed 2 rows per f2 register pair (loop-invariant),
//   target scalars broadcast from the LDS-loaded pairs with op_sel/op_sel_hi
//   (no splat movs). 6 pk_fma + 2 v_min3 per (2 targets x 2 rows) = 2.0 instr/pair.

#define NB 16
#define NP 4096
#define NPTS 65536          // NB*NP per direction
#define THREADS 256
#define ROWS 16             // query rows per thread
#define PAIRS 8             // ROWS/2 packed f2 pairs
#define JT 128              // targets staged in LDS per block
#define TTILES 32           // NP/JT
#define INV128 0.0078125f   // gt normalize: c/128 - 1

typedef __attribute__((ext_vector_type(2))) float f2;
typedef __attribute__((ext_vector_type(4))) float f4;

__global__ __launch_bounds__(256) void init_kernel(unsigned int* __restrict__ mins,
                                                   float* __restrict__ out) {
    int i = blockIdx.x * 1024 + threadIdx.x * 4;   // 128 blocks cover 131072
    uint4* p = (uint4*)(mins + i);
    *p = make_uint4(0x7F800000u, 0x7F800000u, 0x7F800000u, 0x7F800000u); // +inf
    if (blockIdx.x == 0 && threadIdx.x == 0) out[0] = 0.0f;
}

// grid = 1024 blocks: dir = bid>>9, b = (bid>>5)&15, tt = bid&31.
// 256 threads x 16 rows cover all 4096 queries of the batch; each block mins
// over its 128-target LDS chunk; cross-chunk combine via atomicMin on uint bits.
__global__ __launch_bounds__(THREADS, 4) void chamfer_kernel(const float* __restrict__ gen,
                                                             const float* __restrict__ label,
                                                             unsigned int* __restrict__ mins) {
    __shared__ f4 sy[JT];   // (-2x, -2y, -2z, |t|^2) per target

    int bid = blockIdx.x;
    const int dir = bid >> 9;
    const int b   = (bid >> 5) & 15;
    const int tt  = bid & 31;
    const int t   = threadIdx.x;
    const int base = b * NP;

    // --- stage JT=128 targets (threads 0..127) ---
    if (t < JT) {
        int tg = base + tt * JT + t;
        float x, y, z;
        if (dir == 0) {
            const float* row = label + (size_t)tg * 5;
            x = fmaf(row[1], INV128, -1.0f);
            y = fmaf(row[2], INV128, -1.0f);
            z = fmaf(row[3], INV128, -1.0f);
        } else {
            const float* row = gen + (size_t)tg * 3;
            x = row[0]; y = row[1]; z = row[2];
        }
        f4 v;
        v.x = -2.0f * x; v.y = -2.0f * y; v.z = -2.0f * z;
        v.w = fmaf(x, x, fmaf(y, y, z * z));
        sy[t] = v;
    }

    // --- load 16 query rows as 8 packed f2 pairs (rows 2p, 2p+1 strided 256) ---
    f2 qx[PAIRS], qy[PAIRS], qz[PAIRS];
    float mn0[PAIRS], mn1[PAIRS];
    #pragma unroll
    for (int p = 0; p < PAIRS; ++p) {
        #pragma unroll
        for (int h = 0; h < 2; ++h) {
            int qi = base + t + (2 * p + h) * 256;
            float x, y, z;
            if (dir == 0) {
                const float* row = gen + (size_t)qi * 3;
                x = row[0]; y = row[1]; z = row[2];
            } else {
                const float* row = label + (size_t)qi * 5;
                x = fmaf(row[1], INV128, -1.0f);
                y = fmaf(row[2], INV128, -1.0f);
                z = fmaf(row[3], INV128, -1.0f);
            }
            if (h == 0) { qx[p].x = x; qy[p].x = y; qz[p].x = z; }
            else        { qx[p].y = x; qy[p].y = y; qz[p].y = z; }
        }
        mn0[p] = __int_as_float(0x7F800000);
        mn1[p] = __int_as_float(0x7F800000);
    }
    __syncthreads();

    // --- inner loop: 2 targets/iter, register double-buffered broadcast reads.
    // Per target: c01 = (-2x,-2y) pair, c23 = (-2z,|t|^2) pair.
    // a = pk_fma(qx, bcast(c01.lo), bcast(c23.hi))   ; -2x*q.x + |t|^2
    // a = pk_fma(qy, bcast(c01.hi), a)               ; + -2y*q.y
    // a = pk_fma(qz, bcast(c23.lo), a)               ; + -2z*q.z
    const f2* syp = (const f2*)sy;
    f2 c01a = syp[0], c23a = syp[1], c01b = syp[2], c23b = syp[3];
    #pragma unroll 2
    for (int j = 0; j < JT; j += 2) {
        int jn = (j + 2) & (JT - 1);        // wrap: last prefetch unused
        f2 n01a = syp[2 * jn],     n23a = syp[2 * jn + 1];
        f2 n01b = syp[2 * jn + 2], n23b = syp[2 * jn + 3];

        #pragma unroll
        for (int p = 0; p < PAIRS; ++p) {
            f2 a, bv;
            asm("v_pk_fma_f32 %0, %1, %2, %3 op_sel:[0,0,1] op_sel_hi:[1,0,1]"
                : "=v"(a) : "v"(qx[p]), "v"(c01a), "v"(c23a));
            asm("v_pk_fma_f32 %0, %1, %2, %0 op_sel:[0,1,0] op_sel_hi:[1,1,1]"
                : "+v"(a) : "v"(qy[p]), "v"(c01a));
            asm("v_pk_fma_f32 %0, %1, %2, %0 op_sel:[0,0,0] op_sel_hi:[1,0,1]"
                : "+v"(a) : "v"(qz[p]), "v"(c23a));
            asm("v_pk_fma_f32 %0, %1, %2, %3 op_sel:[0,0,1] op_sel_hi:[1,0,1]"
                : "=v"(bv) : "v"(qx[p]), "v"(c01b), "v"(c23b));
            asm("v_pk_fma_f32 %0, %1, %2, %0 op_sel:[0,1,0] op_sel_hi:[1,1,1]"
                : "+v"(bv) : "v"(qy[p]), "v"(c01b));
            asm("v_pk_fma_f32 %0, %1, %2, %0 op_sel:[0,0,0] op_sel_hi:[1,0,1]"
                : "+v"(bv) : "v"(qz[p]), "v"(c23b));
            asm("v_min3_f32 %0, %1, %2, %0" : "+v"(mn0[p]) : "v"(a.x), "v"(bv.x));
            asm("v_min3_f32 %0, %1, %2, %0" : "+v"(mn1[p]) : "v"(a.y), "v"(bv.y));
        }
        c01a = n01a; c23a = n23a; c01b = n01b; c23b = n23b;
    }

    // --- epilogue: add |q|^2 (recomputed), clamp >=0, atomicMin on uint bits ---
    unsigned int* om = mins + dir * NPTS;
    #pragma unroll
    for (int p = 0; p < PAIRS; ++p) {
        float q2l = fmaf(qx[p].x, qx[p].x, fmaf(qy[p].x, qy[p].x, qz[p].x * qz[p].x));
        float q2h = fmaf(qx[p].y, qx[p].y, fmaf(qy[p].y, qy[p].y, qz[p].y * qz[p].y));
        float d0 = fmaxf(mn0[p] + q2l, 0.0f);
        float d1 = fmaxf(mn1[p] + q2h, 0.0f);
        atomicMin(&om[base + t + (2 * p) * 256],     __float_as_uint(d0));
        atomicMin(&om[base + t + (2 * p + 1) * 256], __float_as_uint(d1));
    }
}

__global__ __launch_bounds__(256) void reduce_kernel(const unsigned int* __restrict__ mins,
                                                     float* __restrict__ out) {
    int i = blockIdx.x * 1024 + threadIdx.x * 4;   // 128 blocks cover 131072
    const float4 v = *(const float4*)((const float*)mins + i);
    float s = (v.x + v.y) + (v.z + v.w);
    #pragma unroll
    for (int off = 32; off > 0; off >>= 1) s += __shfl_down(s, off);
    __shared__ float wsum[4];
    int w = threadIdx.x >> 6;
    if ((threadIdx.x & 63) == 0) wsum[w] = s;
    __syncthreads();
    if (threadIdx.x == 0) {
        atomicAdd(out, (wsum[0] + wsum[1] + wsum[2] + wsum[3]) * (1.0f / 65536.0f));
    }
}

extern "C" void kernel_launch(void* const* d_in, const int* in_sizes, int n_in,
                              void* d_out, int out_size, void* d_ws, size_t ws_size,
                              hipStream_t stream) {
    const float* gen   = (const float*)d_in[0];   // [B*P, 3] fp32
    // d_in[1] = batch_gen (int32) — unused: segments are contiguous equal-size
    const float* label = (const float*)d_in[2];   // [B*Q, 5] fp32
    unsigned int* mins = (unsigned int*)d_ws;     // 131072 uints = 512 KB
    float* out = (float*)d_out;

    init_kernel<<<128, 256, 0, stream>>>(mins, out);
    chamfer_kernel<<<2 * NB * TTILES, THREADS, 0, stream>>>(gen, label, mins);
    reduce_kernel<<<128, 256, 0, stream>>>(mins, out);
}

// Round 5
// 100.120 us; speedup vs baseline: 1.0505x; 1.0445x over previous
//
#include <hip/hip_runtime.h>

// Chamfer reconstruction loss, B=16, P=Q=4096, 3-D points, via bf16 MFMA.
// d(i,j) = |q_i|^2 + |t_j|^2 - 2 q_i.t_j.  The cross term + |t|^2 come out of
// one v_mfma_f32_32x32x16_bf16 per 32x32 tile:
//   A (queries, M=32): k0-2 = a, k3-5 = a, k6-7 = 1.0      a = bf16(-2q)
//   B (targets, N=32): k0-2 = t_hi, k3-5 = t_lo, k6-7 = (|t|^2)_hi/lo
//   => C = -2 q~ . t + |t|^2   (t exact via hi/lo split, fp32 accum)
// Query rounding error 2(q~-q).t is per-query-constant -> cancels in argmin
// and averages out across 131072 points (~1e-5 final error).
// Each block: packs its (dir,batch)'s 4096 targets into LDS once, each of its
// 4 waves owns 32 query rows and streams all 128 col-tiles -> complete row-mins
// in-register (no global atomics). Block partial sums -> ws, then 1-block reduce.

#define NB 16
#define NP 4096
#define THREADS 256
#define INV128 0.0078125f   // gt normalize: c/128 - 1
#define FINF __int_as_float(0x7F800000)

typedef __attribute__((ext_vector_type(8)))  short bf16x8;
typedef __attribute__((ext_vector_type(16))) float f32x16;

__device__ __forceinline__ short bf16rne(float f) {
    unsigned u = __float_as_uint(f);
    return (short)((u + 0x7FFFu + ((u >> 16) & 1u)) >> 16);
}
__device__ __forceinline__ float bf2f(short s) {
    return __uint_as_float(((unsigned)(unsigned short)s) << 16);
}

// grid = 1024: dir = bid>>9, b = (bid>>5)&15, qblk = bid&31 (128 queries/block).
__global__ __launch_bounds__(THREADS) void chamfer_kernel(const float* __restrict__ gen,
                                                          const float* __restrict__ label,
                                                          float* __restrict__ partial) {
    // 64KB pack + 1KB pad (zero line for high-half lanes + dead-prefetch overrun)
    __shared__ short spack[NP * 8 + 1024];
    __shared__ float wpart[8];

    int bid = blockIdx.x;
    const int dir  = bid >> 9;
    const int b    = (bid >> 5) & 15;
    const int qblk = bid & 31;
    const int tid  = threadIdx.x;
    const int lane = tid & 63;
    const int wave = tid >> 6;
    const int base = b * NP;

    if (tid < 8) spack[NP * 8 + tid] = 0;   // zero line

    // ---- pack 4096 targets: [t_hi xyz, t_lo xyz, t2_hi, t2_lo] as bf16x8 ----
    #pragma unroll 4
    for (int k = 0; k < 16; ++k) {
        int j = tid + k * 256;
        float x, y, z;
        if (dir == 0) {                       // targets = normalized gt
            const float* row = label + (size_t)(base + j) * 5;
            x = fmaf(row[1], INV128, -1.0f);
            y = fmaf(row[2], INV128, -1.0f);
            z = fmaf(row[3], INV128, -1.0f);
        } else {                              // targets = raw gen
            const float* g = gen + (size_t)(base + j) * 3;
            x = g[0]; y = g[1]; z = g[2];
        }
        float t2 = fmaf(x, x, fmaf(y, y, z * z));
        short xh = bf16rne(x), yh = bf16rne(y), zh = bf16rne(z);
        short xl = bf16rne(x - bf2f(xh));
        short yl = bf16rne(y - bf2f(yh));
        short zl = bf16rne(z - bf2f(zh));
        short th = bf16rne(t2);
        short tl = bf16rne(t2 - bf2f(th));
        bf16x8 v = {xh, yh, zh, xl, yl, zl, th, tl};
        *(bf16x8*)(spack + j * 8) = v;
    }

    // ---- per-lane query: A-frag rows = lane&31; high half (k8-15) is zero ----
    const int qrow = base + qblk * 128 + wave * 32 + (lane & 31);
    float q2 = 0.0f;
    bf16x8 afrag = (bf16x8)(short)0;
    if (lane < 32) {
        float x, y, z;
        if (dir == 0) {                       // queries = raw gen
            const float* g = gen + (size_t)qrow * 3;
            x = g[0]; y = g[1]; z = g[2];
        } else {                              // queries = normalized gt
            const float* row = label + (size_t)qrow * 5;
            x = fmaf(row[1], INV128, -1.0f);
            y = fmaf(row[2], INV128, -1.0f);
            z = fmaf(row[3], INV128, -1.0f);
        }
        q2 = fmaf(x, x, fmaf(y, y, z * z));   // exact fp32, added after the min
        short ax = bf16rne(-2.0f * x), ay = bf16rne(-2.0f * y), az = bf16rne(-2.0f * z);
        const short one = 0x3F80;             // bf16 1.0
        bf16x8 a = {ax, ay, az, ax, ay, az, one, one};
        afrag = a;
    }
    __syncthreads();

    // ---- stream 128 col-tiles, 2 per iteration, register-double-buffered ----
    const short* pa = (lane < 32) ? (spack + (lane & 31) * 8)       : (spack + NP * 8);
    const short* pb = (lane < 32) ? (spack + (lane & 31) * 8 + 256) : (spack + NP * 8);
    const int step = (lane < 32) ? 512 : 0;   // 2 tiles = 64 cols * 8 shorts

    float mn[16];
    #pragma unroll
    for (int r = 0; r < 16; ++r) mn[r] = FINF;
    const f32x16 zc = {};                     // zero C operand

    bf16x8 bA = *(const bf16x8*)pa;
    bf16x8 bB = *(const bf16x8*)pb;
    #pragma unroll 2
    for (int it = 0; it < 64; ++it) {
        pa += step; pb += step;
        bf16x8 nA = *(const bf16x8*)pa;       // last iter reads pad (dead)
        bf16x8 nB = *(const bf16x8*)pb;
        f32x16 ca = __builtin_amdgcn_mfma_f32_32x32x16_bf16(afrag, bA, zc, 0, 0, 0);
        f32x16 cb = __builtin_amdgcn_mfma_f32_32x32x16_bf16(afrag, bB, zc, 0, 0, 0);
        #pragma unroll
        for (int r = 0; r < 16; ++r)
            asm("v_min3_f32 %0, %1, %2, %0" : "+v"(mn[r]) : "v"(ca[r]), "v"(cb[r]));
        bA = nA; bB = nB;
    }

    // ---- fold the 32 column-classes (butterfly within each 32-lane half) ----
    #pragma unroll
    for (int m = 1; m <= 16; m <<= 1) {
        #pragma unroll
        for (int r = 0; r < 16; ++r)
            mn[r] = fminf(mn[r], __shfl_xor(mn[r], m, 64));
    }

    // ---- d(row) = mn + |q_row|^2 ; sum this half's 16 rows ----
    // C/D layout: row = (r&3) + 8*(r>>2) + 4*(lane>>5), col = lane&31.
    float s = 0.0f;
    const int h4 = (lane >> 5) * 4;
    #pragma unroll
    for (int r = 0; r < 16; ++r) {
        int row = (r & 3) + 8 * (r >> 2) + h4;
        s += mn[r] + __shfl(q2, row, 64);     // q2 lives at lane == row (low half)
    }
    if ((lane & 31) == 0) wpart[wave * 2 + (lane >> 5)] = s;
    __syncthreads();
    if (tid == 0) {
        float t = 0.0f;
        #pragma unroll
        for (int i = 0; i < 8; ++i) t += wpart[i];
        partial[blockIdx.x] = t;              // plain store, no init needed
    }
}

__global__ __launch_bounds__(256) void reduce_kernel(const float* __restrict__ partial,
                                                     float* __restrict__ out) {
    int i = threadIdx.x;
    float s = (partial[i] + partial[i + 256]) + (partial[i + 512] + partial[i + 768]);
    #pragma unroll
    for (int off = 32; off > 0; off >>= 1) s += __shfl_down(s, off, 64);
    __shared__ float ws4[4];
    if ((i & 63) == 0) ws4[i >> 6] = s;
    __syncthreads();
    if (i == 0) out[0] = ((ws4[0] + ws4[1]) + (ws4[2] + ws4[3])) * (1.0f / 65536.0f);
}

extern "C" void kernel_launch(void* const* d_in, const int* in_sizes, int n_in,
                              void* d_out, int out_size, void* d_ws, size_t ws_size,
                              hipStream_t stream) {
    const float* gen   = (const float*)d_in[0];   // [B*P, 3] fp32
    // d_in[1] = batch_gen (int32) — unused: segments are contiguous equal-size
    const float* label = (const float*)d_in[2];   // [B*Q, 5] fp32
    float* partial = (float*)d_ws;                // 1024 floats = 4 KB
    float* out = (float*)d_out;

    chamfer_kernel<<<1024, THREADS, 0, stream>>>(gen, label, partial);
    reduce_kernel<<<1, 256, 0, stream>>>(partial, out);
}

// Round 9
// 89.836 us; speedup vs baseline: 1.1707x; 1.1145x over previous
//
#include <hip/hip_runtime.h>

// Chamfer reconstruction loss, B=16, P=Q=4096, 3-D points, via bf16 MFMA.
// d(i,j) = |q_i|^2 + |t_j|^2 - 2 q_i.t_j; cross term + |t|^2 via one
// v_mfma_f32_32x32x16_bf16 per 32x32 tile (A: a=bf16(-2q) twice + 1.0;
// B: t_hi, t_lo, |t|^2 hi/lo; fp32 accum). Query rounding error is
// per-row-constant -> cancels in argmin, averages out in the mean.
//
// R9: EXACT R5 geometry (256 threads / 4 waves, single 64KB pack pass, one
// __syncthreads, verified epilogue) — the R6/R7/R8 geometry changes all
// failed. Register-level changes only:
//  (1) streaming loop widened to 4 tiles/iter (4 ds_read_b128 in flight,
//      32 iters) to cover the ~120cyc LDS latency;
//  (2) each block processes 2 query-blocks sequentially (outer register
//      loop) -> grid 512 = one launch round, total pack work halved.

#define NB 16
#define NP 4096
#define THREADS 256
#define INV128 0.0078125f   // gt normalize: c/128 - 1
#define FINF __int_as_float(0x7F800000)

typedef __attribute__((ext_vector_type(8)))  short bf16x8;
typedef __attribute__((ext_vector_type(16))) float f32x16;

__device__ __forceinline__ short bf16rne(float f) {
    unsigned u = __float_as_uint(f);
    return (short)((u + 0x7FFFu + ((u >> 16) & 1u)) >> 16);
}
__device__ __forceinline__ float bf2f(short s) {
    return __uint_as_float(((unsigned)(unsigned short)s) << 16);
}

// grid = 512: dir = bid>>8, b = (bid>>4)&15, qpair = bid&15.
// Block covers qblks {2*qpair, 2*qpair+1} (128 queries each, R5 geometry).
__global__ __launch_bounds__(THREADS) void chamfer_kernel(const float* __restrict__ gen,
                                                          const float* __restrict__ label,
                                                          float* __restrict__ partial) {
    // 64KB pack + zero line + prefetch-overrun pad (R5 layout, pad widened)
    __shared__ short spack[NP * 8 + 1280];
    __shared__ float wpart[8];

    const int bid   = blockIdx.x;
    const int dir   = bid >> 8;
    const int b     = (bid >> 4) & 15;
    const int qpair = bid & 15;
    const int tid   = threadIdx.x;
    const int lane  = tid & 63;
    const int wave  = tid >> 6;           // 0..3
    const int base  = b * NP;

    if (tid < 8) spack[NP * 8 + tid] = 0;   // zero line for high-half lanes

    // ---- pack 4096 targets: [t_hi xyz, t_lo xyz, t2_hi, t2_lo] bf16x8 ----
    #pragma unroll 4
    for (int k = 0; k < 16; ++k) {
        int j = tid + k * 256;
        float x, y, z;
        if (dir == 0) {                       // targets = normalized gt
            const float* row = label + (size_t)(base + j) * 5;
            x = fmaf(row[1], INV128, -1.0f);
            y = fmaf(row[2], INV128, -1.0f);
            z = fmaf(row[3], INV128, -1.0f);
        } else {                              // targets = raw gen
            const float* g = gen + (size_t)(base + j) * 3;
            x = g[0]; y = g[1]; z = g[2];
        }
        float t2 = fmaf(x, x, fmaf(y, y, z * z));
        short xh = bf16rne(x), yh = bf16rne(y), zh = bf16rne(z);
        short xl = bf16rne(x - bf2f(xh));
        short yl = bf16rne(y - bf2f(yh));
        short zl = bf16rne(z - bf2f(zh));
        short th = bf16rne(t2);
        short tl = bf16rne(t2 - bf2f(th));
        bf16x8 v = {xh, yh, zh, xl, yl, zl, th, tl};
        *(bf16x8*)(spack + j * 8) = v;
    }
    __syncthreads();                          // spack is read-only from here on

    float sacc = 0.0f;                        // per-thread sum over both qblks
    const f32x16 zc = {};

    #pragma unroll 1
    for (int sub = 0; sub < 2; ++sub) {
        const int qblk = qpair * 2 + sub;

        // ---- per-lane query fragment: rows = lane&31, k8-15 zero ----
        const int qrow = base + qblk * 128 + wave * 32 + (lane & 31);
        float q2 = 0.0f;
        bf16x8 afrag = (bf16x8)(short)0;
        if (lane < 32) {
            float x, y, z;
            if (dir == 0) {                   // queries = raw gen
                const float* g = gen + (size_t)qrow * 3;
                x = g[0]; y = g[1]; z = g[2];
            } else {                          // queries = normalized gt
                const float* row = label + (size_t)qrow * 5;
                x = fmaf(row[1], INV128, -1.0f);
                y = fmaf(row[2], INV128, -1.0f);
                z = fmaf(row[3], INV128, -1.0f);
            }
            q2 = fmaf(x, x, fmaf(y, y, z * z));  // exact fp32, added after min
            short ax = bf16rne(-2.0f * x), ay = bf16rne(-2.0f * y), az = bf16rne(-2.0f * z);
            const short one = 0x3F80;         // bf16 1.0
            bf16x8 a = {ax, ay, az, ax, ay, az, one, one};
            afrag = a;
        }

        float mn[16];
        #pragma unroll
        for (int r = 0; r < 16; ++r) mn[r] = FINF;

        // ---- stream 128 col-tiles, 4/iter, register double-buffered ----
        const short* zl = spack + NP * 8;
        const short* p0 = (lane < 32) ? (spack + (lane & 31) * 8)       : zl;
        const short* p1 = (lane < 32) ? (spack + (lane & 31) * 8 + 256) : zl;
        const short* p2 = (lane < 32) ? (spack + (lane & 31) * 8 + 512) : zl;
        const short* p3 = (lane < 32) ? (spack + (lane & 31) * 8 + 768) : zl;
        const int step = (lane < 32) ? 1024 : 0;   // 4 tiles = 128 cols * 8 shorts

        bf16x8 b0 = *(const bf16x8*)p0;
        bf16x8 b1 = *(const bf16x8*)p1;
        bf16x8 b2 = *(const bf16x8*)p2;
        bf16x8 b3 = *(const bf16x8*)p3;
        #pragma unroll 2
        for (int it = 0; it < 32; ++it) {
            p0 += step; p1 += step; p2 += step; p3 += step;
            bf16x8 n0 = *(const bf16x8*)p0;   // last iter: dead reads into pad
            bf16x8 n1 = *(const bf16x8*)p1;
            bf16x8 n2 = *(const bf16x8*)p2;
            bf16x8 n3 = *(const bf16x8*)p3;
            f32x16 c0 = __builtin_amdgcn_mfma_f32_32x32x16_bf16(afrag, b0, zc, 0, 0, 0);
            f32x16 c1 = __builtin_amdgcn_mfma_f32_32x32x16_bf16(afrag, b1, zc, 0, 0, 0);
            f32x16 c2 = __builtin_amdgcn_mfma_f32_32x32x16_bf16(afrag, b2, zc, 0, 0, 0);
            f32x16 c3 = __builtin_amdgcn_mfma_f32_32x32x16_bf16(afrag, b3, zc, 0, 0, 0);
            #pragma unroll
            for (int r = 0; r < 16; ++r) {
                asm("v_min3_f32 %0, %1, %2, %0" : "+v"(mn[r]) : "v"(c0[r]), "v"(c1[r]));
                asm("v_min3_f32 %0, %1, %2, %0" : "+v"(mn[r]) : "v"(c2[r]), "v"(c3[r]));
            }
            b0 = n0; b1 = n1; b2 = n2; b3 = n3;
        }

        // ---- fold 32 column-classes (butterfly within each 32-lane half) ----
        #pragma unroll
        for (int m = 1; m <= 16; m <<= 1) {
            #pragma unroll
            for (int r = 0; r < 16; ++r)
                mn[r] = fminf(mn[r], __shfl_xor(mn[r], m, 64));
        }

        // ---- d(row) = mn + |q_row|^2 ; sum this half's 16 rows ----
        // C/D layout: row = (r&3) + 8*(r>>2) + 4*(lane>>5), col = lane&31.
        const int h4 = (lane >> 5) * 4;
        #pragma unroll
        for (int r = 0; r < 16; ++r) {
            int row = (r & 3) + 8 * (r >> 2) + h4;
            sacc += mn[r] + __shfl(q2, row, 64);  // q2 lives at lane==row (low half)
        }
    }

    // ---- epilogue: verbatim R5 ----
    if ((lane & 31) == 0) wpart[wave * 2 + (lane >> 5)] = sacc;
    __syncthreads();
    if (tid == 0) {
        float t = 0.0f;
        #pragma unroll
        for (int i = 0; i < 8; ++i) t += wpart[i];
        partial[bid] = t;                     // plain store, no init needed
    }
}

__global__ __launch_bounds__(256) void reduce_kernel(const float* __restrict__ partial,
                                                     float* __restrict__ out) {
    int i = threadIdx.x;
    float s = partial[i] + partial[i + 256];  // 512 block partials
    #pragma unroll
    for (int off = 32; off > 0; off >>= 1) s += __shfl_down(s, off, 64);
    __shared__ float ws4[4];
    if ((i & 63) == 0) ws4[i >> 6] = s;
    __syncthreads();
    if (i == 0) out[0] = ((ws4[0] + ws4[1]) + (ws4[2] + ws4[3])) * (1.0f / 65536.0f);
}

extern "C" void kernel_launch(void* const* d_in, const int* in_sizes, int n_in,
                              void* d_out, int out_size, void* d_ws, size_t ws_size,
                              hipStream_t stream) {
    const float* gen   = (const float*)d_in[0];   // [B*P, 3] fp32
    // d_in[1] = batch_gen (int32) — unused: segments are contiguous equal-size
    const float* label = (const float*)d_in[2];   // [B*Q, 5] fp32
    float* partial = (float*)d_ws;                // 512 floats = 2 KB
    float* out = (float*)d_out;

    chamfer_kernel<<<512, THREADS, 0, stream>>>(gen, label, partial);
    reduce_kernel<<<1, 256, 0, stream>>>(partial, out);
}